// Round 1
// baseline (1798.895 us; speedup 1.0000x reference)
//
#include <hip/hip_runtime.h>
#include <math.h>

// ---------------- problem constants ----------------
constexpr int B  = 128;
constexpr int N  = 1024;
constexpr int E  = 16384;
constexpr int FIN = 32;
constexpr int H  = 64;
constexpr int K1 = 820, K2 = 656, K3 = 525;
constexpr int NCLS = 10;

// ---------------- edge aggregation: agg[dst] += x[src] * w ----------------
// One graph is split across NSPLIT blocks, each owning FB of FTOT features.
// Scatter target lives in LDS (row stride FB+1 to spread banks).
template<int NPG, int FTOT, int FB, bool HASW>
__global__ __launch_bounds__(256) void agg_kernel(
    const float* __restrict__ xin, const int* __restrict__ src,
    const int* __restrict__ dst, const float* __restrict__ wgt,
    float* __restrict__ agg)
{
    constexpr int NSPLIT = FTOT / FB;
    constexpr int STRIDE = FB + 1;
    const int g    = blockIdx.x / NSPLIT;
    const int half = blockIdx.x % NSPLIT;
    extern __shared__ float lds[];
    const int tid = threadIdx.x;
    for (int i = tid; i < NPG * STRIDE; i += 256) lds[i] = 0.f;
    __syncthreads();
    const size_t ebase = (size_t)g * E;
    const int nodebase = g * NPG;
    for (int e = tid; e < E; e += 256) {
        const int s = src[ebase + e];
        const int d = dst[ebase + e];
        if (s < 0 || d < 0) continue;               // masked edge
        const float w = HASW ? wgt[ebase + e] : 1.0f;
        const float4* xr = (const float4*)(xin + (size_t)s * FTOT + half * FB);
        float* ar = lds + (d - nodebase) * STRIDE;
        #pragma unroll
        for (int q = 0; q < FB / 4; ++q) {
            float4 v = xr[q];
            atomicAdd(ar + 4 * q + 0, v.x * w);
            atomicAdd(ar + 4 * q + 1, v.y * w);
            atomicAdd(ar + 4 * q + 2, v.z * w);
            atomicAdd(ar + 4 * q + 3, v.w * w);
        }
    }
    __syncthreads();
    for (int i = tid; i < NPG * FB; i += 256) {
        const int node = i / FB, f = i % FB;
        agg[((size_t)nodebase + node) * FTOT + half * FB + f] = lds[node * STRIDE + f];
    }
}

// ---------------- fused node linear + relu + pooling score ----------------
// h = relu(agg@wr.T + x@wk.T + br);  score = tanh(h.pw / ||pw||)
// one wave per node, 16 nodes per block.
template<int KIN>
__global__ __launch_bounds__(256) void lin_score_kernel(
    const float* __restrict__ agg, const float* __restrict__ xin,
    const float* __restrict__ wr,  const float* __restrict__ br,
    const float* __restrict__ wk,  const float* __restrict__ pw,
    float* __restrict__ h, float* __restrict__ score)
{
    __shared__ float s_wrT[KIN * 64], s_wkT[KIN * 64], s_pw[64], s_br[64];
    const int tid = threadIdx.x;
    for (int i = tid; i < KIN * 64; i += 256) {
        const int k = i / 64, o = i % 64;          // transposed: [k][o]
        s_wrT[i] = wr[o * KIN + k];
        s_wkT[i] = wk[o * KIN + k];
    }
    if (tid < 64) { s_pw[tid] = pw[tid]; s_br[tid] = br[tid]; }
    __syncthreads();
    const int wave = tid >> 6, lane = tid & 63;
    const float pwv = s_pw[lane];
    float nrm2 = pwv * pwv;
    #pragma unroll
    for (int off = 32; off; off >>= 1) nrm2 += __shfl_xor(nrm2, off);
    const float inv_norm = rsqrtf(nrm2);

    #pragma unroll
    for (int rep = 0; rep < 4; ++rep) {
        const int node = (blockIdx.x << 4) + (rep << 2) + wave;
        const float* ar = agg + (size_t)node * KIN;
        const float* xr = xin + (size_t)node * KIN;
        float acc = s_br[lane];
        #pragma unroll
        for (int k = 0; k < KIN; k += 4) {
            float4 a4 = *(const float4*)(ar + k);
            float4 x4 = *(const float4*)(xr + k);
            acc = fmaf(a4.x, s_wrT[(k + 0) * 64 + lane], acc);
            acc = fmaf(a4.y, s_wrT[(k + 1) * 64 + lane], acc);
            acc = fmaf(a4.z, s_wrT[(k + 2) * 64 + lane], acc);
            acc = fmaf(a4.w, s_wrT[(k + 3) * 64 + lane], acc);
            acc = fmaf(x4.x, s_wkT[(k + 0) * 64 + lane], acc);
            acc = fmaf(x4.y, s_wkT[(k + 1) * 64 + lane], acc);
            acc = fmaf(x4.z, s_wkT[(k + 2) * 64 + lane], acc);
            acc = fmaf(x4.w, s_wkT[(k + 3) * 64 + lane], acc);
        }
        const float hv = fmaxf(acc, 0.f);
        h[(size_t)node * 64 + lane] = hv;
        float p = hv * pwv;
        #pragma unroll
        for (int off = 32; off; off >>= 1) p += __shfl_xor(p, off);
        if (lane == 0) score[node] = tanhf(p * inv_norm);
    }
}

// ---------------- per-graph top-k via bitonic sort (descending) ----------------
// Output set/order within set doesn't affect the final result (readout is
// max/mean, relabeling consistent), so an unstable sort is fine.
template<int NREAL, int KSEL>
__global__ __launch_bounds__(512) void topk_kernel(
    const float* __restrict__ score, int* __restrict__ sel, int* __restrict__ nidx)
{
    __shared__ float sval[1024];
    __shared__ int   sidx[1024];
    const int g = blockIdx.x, tid = threadIdx.x;
    for (int i = tid; i < 1024; i += 512) {
        if (i < NREAL) { sval[i] = score[(size_t)g * NREAL + i]; }
        else           { sval[i] = -2.0f; }        // tanh >= -1 > pad
        sidx[i] = i;
    }
    __syncthreads();
    for (int k = 2; k <= 1024; k <<= 1)
        for (int j = k >> 1; j > 0; j >>= 1) {
            for (int i = tid; i < 1024; i += 512) {
                const int l = i ^ j;
                if (l > i) {
                    const float a = sval[i], bv = sval[l];
                    const bool up = ((i & k) == 0);
                    if ((up && a < bv) || (!up && a > bv)) {
                        sval[i] = bv; sval[l] = a;
                        const int t = sidx[i]; sidx[i] = sidx[l]; sidx[l] = t;
                    }
                }
            }
            __syncthreads();
        }
    for (int j = tid; j < NREAL; j += 512) {
        const int node = sidx[j];
        if (j < KSEL) {
            sel[(size_t)g * KSEL + j] = node;
            nidx[(size_t)g * NREAL + node] = g * KSEL + j;
        } else {
            nidx[(size_t)g * NREAL + node] = -1;
        }
    }
}

// ---------------- pooled gather: xg[new] = h[old] * score[old] ----------------
__global__ __launch_bounds__(256) void gather_kernel(
    const float* __restrict__ h, const float* __restrict__ score,
    const int* __restrict__ sel, float* __restrict__ xg, int KSEL, int NPREV)
{
    const size_t i = (size_t)blockIdx.x * 256 + threadIdx.x;  // < B*KSEL*64
    const int f = (int)(i & 63);
    const size_t n = i >> 6;
    const int g = (int)(n / KSEL);
    const int old = sel[n];
    const size_t oldg = (size_t)g * NPREV + old;
    xg[i] = h[oldg * 64 + f] * score[oldg];
}

// ---------------- edge remap through new_idx (-1 = dropped) ----------------
__global__ __launch_bounds__(256) void remap_kernel(
    const int* __restrict__ src_in, const int* __restrict__ dst_in,
    const int* __restrict__ nidx, int* __restrict__ src_out, int* __restrict__ dst_out)
{
    const size_t e = (size_t)blockIdx.x * 256 + threadIdx.x;
    const int s = src_in[e], d = dst_in[e];
    src_out[e] = (s >= 0) ? nidx[s] : -1;
    dst_out[e] = (d >= 0) ? nidx[d] : -1;
}

// ---------------- readout: concat(max, mean) over k nodes ----------------
__global__ __launch_bounds__(256) void readout_kernel(
    const float* __restrict__ xg, float* __restrict__ out, int KSEL)
{
    const int g = blockIdx.x, tid = threadIdx.x;
    const int f = tid & 63, jc = tid >> 6;      // 4 j-chunks x 64 feats
    float mx = -3.4e38f, sm = 0.f;
    #pragma unroll 4
    for (int j = jc; j < KSEL; j += 4) {
        const float v = xg[((size_t)g * KSEL + j) * 64 + f];
        mx = fmaxf(mx, v); sm += v;
    }
    __shared__ float smx[256], ssm[256];
    smx[tid] = mx; ssm[tid] = sm;
    __syncthreads();
    if (tid < 64) {
        mx = fmaxf(fmaxf(smx[tid], smx[tid + 64]), fmaxf(smx[tid + 128], smx[tid + 192]));
        sm = ssm[tid] + ssm[tid + 64] + ssm[tid + 128] + ssm[tid + 192];
        out[g * 128 + tid] = mx;
        out[g * 128 + 64 + tid] = sm / (float)KSEL;
    }
}

// ---------------- final MLP + log_softmax (one wave per graph) ----------------
__global__ __launch_bounds__(64) void mlp_kernel(
    const float* __restrict__ x1, const float* __restrict__ x2, const float* __restrict__ x3,
    const float* __restrict__ w1, const float* __restrict__ b1,
    const float* __restrict__ w2, const float* __restrict__ b2,
    const float* __restrict__ w3, const float* __restrict__ b3,
    const float* __restrict__ w4, const float* __restrict__ b4,
    float* __restrict__ out)
{
    const int g = blockIdx.x, lane = threadIdx.x;
    __shared__ float z[128], a1[64], a2[32], a3[16], y[16], red[2];
    z[lane]      = x1[g * 128 + lane]      + x2[g * 128 + lane]      + x3[g * 128 + lane];
    z[lane + 64] = x1[g * 128 + 64 + lane] + x2[g * 128 + 64 + lane] + x3[g * 128 + 64 + lane];
    __syncthreads();
    float acc = b1[lane];
    #pragma unroll
    for (int k = 0; k < 128; ++k) acc = fmaf(z[k], w1[lane * 128 + k], acc);
    a1[lane] = fmaxf(acc, 0.f);
    __syncthreads();
    if (lane < 32) {
        float a = b2[lane];
        #pragma unroll
        for (int k = 0; k < 64; ++k) a = fmaf(a1[k], w2[lane * 64 + k], a);
        a2[lane] = fmaxf(a, 0.f);
    }
    __syncthreads();
    if (lane < 16) {
        float a = b3[lane];
        #pragma unroll
        for (int k = 0; k < 32; ++k) a = fmaf(a2[k], w3[lane * 32 + k], a);
        a3[lane] = fmaxf(a, 0.f);
    }
    __syncthreads();
    if (lane < NCLS) {
        float a = b4[lane];
        #pragma unroll
        for (int k = 0; k < 16; ++k) a = fmaf(a3[k], w4[lane * 16 + k], a);
        y[lane] = a;
    }
    __syncthreads();
    if (lane == 0) {
        float m = y[0];
        for (int c = 1; c < NCLS; ++c) m = fmaxf(m, y[c]);
        float s = 0.f;
        for (int c = 0; c < NCLS; ++c) s += expf(y[c] - m);
        red[0] = m; red[1] = logf(s);
    }
    __syncthreads();
    if (lane < NCLS) out[g * NCLS + lane] = y[lane] - red[0] - red[1];
}

// ---------------- workspace layout (bytes) ----------------
constexpr size_t OFF_H     = 0;                          // B*N*H f32   = 33.6 MB
constexpr size_t OFF_AGG   = OFF_H     + (size_t)B * N * H * 4;    // 33.6 MB
constexpr size_t OFF_XG    = OFF_AGG   + (size_t)B * N * H * 4;    // B*K1*H f32 = 26.9 MB
constexpr size_t OFF_SCORE = OFF_XG    + (size_t)B * K1 * H * 4;   // B*N f32
constexpr size_t OFF_SEL   = OFF_SCORE + (size_t)B * N * 4;        // B*K1 int
constexpr size_t OFF_NIDX  = OFF_SEL   + (size_t)B * K1 * 4;       // B*N int
constexpr size_t OFF_ESRC  = OFF_NIDX  + (size_t)B * N * 4;        // B*E int
constexpr size_t OFF_EDST  = OFF_ESRC  + (size_t)B * E * 4;        // B*E int
constexpr size_t OFF_X1    = OFF_EDST  + (size_t)B * E * 4;        // B*128 f32
constexpr size_t OFF_X2    = OFF_X1    + (size_t)B * 128 * 4;
constexpr size_t OFF_X3    = OFF_X2    + (size_t)B * 128 * 4;

extern "C" void kernel_launch(void* const* d_in, const int* in_sizes, int n_in,
                              void* d_out, int out_size, void* d_ws, size_t ws_size,
                              hipStream_t stream)
{
    (void)in_sizes; (void)n_in; (void)out_size; (void)ws_size;
    const float* x     = (const float*)d_in[0];
    const int*   eidx  = (const int*)d_in[1];
    const float* eattr = (const float*)d_in[2];
    const int* src0 = eidx;
    const int* dst0 = eidx + (size_t)B * E;
    const float* c1_wr = (const float*)d_in[3],  *c1_br = (const float*)d_in[4];
    const float* c1_wk = (const float*)d_in[5],  *p1_w  = (const float*)d_in[6];
    const float* c2_wr = (const float*)d_in[7],  *c2_br = (const float*)d_in[8];
    const float* c2_wk = (const float*)d_in[9],  *p2_w  = (const float*)d_in[10];
    const float* c3_wr = (const float*)d_in[11], *c3_br = (const float*)d_in[12];
    const float* c3_wk = (const float*)d_in[13], *p3_w  = (const float*)d_in[14];
    const float* l1_w = (const float*)d_in[15], *l1_b = (const float*)d_in[16];
    const float* l2_w = (const float*)d_in[17], *l2_b = (const float*)d_in[18];
    const float* l3_w = (const float*)d_in[19], *l3_b = (const float*)d_in[20];
    const float* l4_w = (const float*)d_in[21], *l4_b = (const float*)d_in[22];

    char* ws = (char*)d_ws;
    float* h     = (float*)(ws + OFF_H);
    float* agg   = (float*)(ws + OFF_AGG);
    float* xg    = (float*)(ws + OFF_XG);
    float* score = (float*)(ws + OFF_SCORE);
    int*   sel   = (int*)  (ws + OFF_SEL);
    int*   nidx  = (int*)  (ws + OFF_NIDX);
    int*   esrc  = (int*)  (ws + OFF_ESRC);
    int*   edst  = (int*)  (ws + OFF_EDST);
    float* x1    = (float*)(ws + OFF_X1);
    float* x2    = (float*)(ws + OFF_X2);
    float* x3    = (float*)(ws + OFF_X3);
    float* out   = (float*)d_out;

    const int nEdgeBlk = (B * E) / 256;  // 8192

    // ---- stage 1 ----
    agg_kernel<N, FIN, 8, true><<<B * 4, 256, N * 9 * 4, stream>>>(x, src0, dst0, eattr, agg);
    lin_score_kernel<FIN><<<(B * N) / 16, 256, 0, stream>>>(agg, x, c1_wr, c1_br, c1_wk, p1_w, h, score);
    topk_kernel<N, K1><<<B, 512, 0, stream>>>(score, sel, nidx);
    gather_kernel<<<(B * K1 * 64) / 256, 256, 0, stream>>>(h, score, sel, xg, K1, N);
    remap_kernel<<<nEdgeBlk, 256, 0, stream>>>(src0, dst0, nidx, esrc, edst);
    readout_kernel<<<B, 256, 0, stream>>>(xg, x1, K1);

    // ---- stage 2 ----
    agg_kernel<K1, H, 16, false><<<B * 4, 256, K1 * 17 * 4, stream>>>(xg, esrc, edst, nullptr, agg);
    lin_score_kernel<H><<<(B * K1) / 16, 256, 0, stream>>>(agg, xg, c2_wr, c2_br, c2_wk, p2_w, h, score);
    topk_kernel<K1, K2><<<B, 512, 0, stream>>>(score, sel, nidx);
    gather_kernel<<<(B * K2 * 64) / 256, 256, 0, stream>>>(h, score, sel, xg, K2, K1);
    remap_kernel<<<nEdgeBlk, 256, 0, stream>>>(esrc, edst, nidx, esrc, edst);  // in-place ok (elementwise)
    readout_kernel<<<B, 256, 0, stream>>>(xg, x2, K2);

    // ---- stage 3 ----
    agg_kernel<K2, H, 16, false><<<B * 4, 256, K2 * 17 * 4, stream>>>(xg, esrc, edst, nullptr, agg);
    lin_score_kernel<H><<<(B * K2) / 16, 256, 0, stream>>>(agg, xg, c3_wr, c3_br, c3_wk, p3_w, h, score);
    topk_kernel<K2, K3><<<B, 512, 0, stream>>>(score, sel, nidx);
    gather_kernel<<<(B * K3 * 64) / 256, 256, 0, stream>>>(h, score, sel, xg, K3, K2);
    readout_kernel<<<B, 256, 0, stream>>>(xg, x3, K3);

    // ---- head ----
    mlp_kernel<<<B, 64, 0, stream>>>(x1, x2, x3, l1_w, l1_b, l2_w, l2_b,
                                     l3_w, l3_b, l4_w, l4_b, out);
}

// Round 7
// 1057.502 us; speedup vs baseline: 1.7011x; 1.7011x over previous
//
#include <hip/hip_runtime.h>
#include <math.h>

// ---------------- problem constants ----------------
constexpr int B  = 128;
constexpr int N  = 1024;
constexpr int E  = 16384;
constexpr int FIN = 32;
constexpr int H  = 64;
constexpr int K1 = 820, K2 = 656, K3 = 525;
constexpr int NCLS = 10;

// ---------------- CSR build: histogram + scan + scatter (1 block/graph) ----
// Optionally remaps edges through nidx (old-global -> new-global, -1 = drop)
// and writes the remapped edge list back out for the next stage's build.
template<int NPG, bool REMAP, bool HASW>
__global__ __launch_bounds__(1024) void build_kernel(
    const int* __restrict__ src_in, const int* __restrict__ dst_in,
    const int* __restrict__ nidx,  const float* __restrict__ w_in,
    int* __restrict__ esrc_out, int* __restrict__ edst_out,
    int* __restrict__ rowoff, int* __restrict__ csr_src, float* __restrict__ csr_w)
{
    __shared__ int cnt[1024];
    __shared__ int excl[1024];
    const int g = blockIdx.x, tid = threadIdx.x;
    cnt[tid] = 0;
    __syncthreads();
    const size_t gE = (size_t)g * E;
    int sreg[16], dreg[16];
    #pragma unroll
    for (int i = 0; i < 16; ++i) {
        const int e = tid + i * 1024;
        int s = src_in[gE + e], d = dst_in[gE + e];
        if (REMAP) {
            s = (s >= 0) ? nidx[s] : -1;
            d = (d >= 0) ? nidx[d] : -1;
            esrc_out[gE + e] = s;
            edst_out[gE + e] = d;
        }
        if (s < 0 || d < 0) { s = -1; d = -1; }
        sreg[i] = s; dreg[i] = d;
        if (d >= 0) atomicAdd(&cnt[d - g * NPG], 1);
    }
    __syncthreads();
    // exclusive scan over NPG counters (Hillis-Steele on 1024, padded)
    const int v = (tid < NPG) ? cnt[tid] : 0;
    excl[tid] = v;
    __syncthreads();
    int run = v;
    for (int dd = 1; dd < 1024; dd <<= 1) {
        const int t = (tid >= dd) ? excl[tid - dd] : 0;
        __syncthreads();
        run += t;
        excl[tid] = run;
        __syncthreads();
    }
    const int ex = run - v;                    // exclusive prefix
    if (tid < NPG) rowoff[(size_t)g * (NPG + 1) + tid] = ex;
    if (tid == NPG - 1) rowoff[(size_t)g * (NPG + 1) + NPG] = run;
    excl[tid] = ex;
    cnt[tid] = 0;
    __syncthreads();
    #pragma unroll
    for (int i = 0; i < 16; ++i) {
        const int d = dreg[i];
        if (d >= 0) {
            const int dl = d - g * NPG;
            const int pos = excl[dl] + atomicAdd(&cnt[dl], 1);
            csr_src[gE + pos] = sreg[i];
            if (HASW) csr_w[gE + pos] = w_in[gE + tid + i * 1024];
        }
    }
}

// ---------------- CSR gather-aggregate: agg[n] = sum_{e in row(n)} w_e * x[src_e]
// one wave per node (8 nodes/wave), lane = feature; no atomics, no LDS.
template<int KIN, int NPG, bool HASW>
__global__ __launch_bounds__(256) void agg_csr_kernel(
    const float* __restrict__ xin, const int* __restrict__ csr_src,
    const float* __restrict__ csr_w, const int* __restrict__ rowoff,
    float* __restrict__ agg)
{
    const int wave = threadIdx.x >> 6, lane = threadIdx.x & 63;
    const int nbase = (blockIdx.x * 4 + wave) * 8;
    #pragma unroll 2
    for (int rep = 0; rep < 8; ++rep) {
        const int n = nbase + rep;
        const int g = n / NPG, nl = n - g * NPG;
        const size_t gE = (size_t)g * E;
        const int start = rowoff[g * (NPG + 1) + nl];
        const int end   = rowoff[g * (NPG + 1) + nl + 1];
        float acc = 0.f;
        for (int j0 = start; j0 < end; j0 += 64) {
            const int m = end - j0 < 64 ? end - j0 : 64;
            const int idx = j0 + (lane < m ? lane : 0);
            const int ids = csr_src[gE + idx];
            float wch = 1.f;
            if (HASW) wch = csr_w[gE + idx];
            if (KIN == 64) {
                for (int jj = 0; jj < m; ++jj) {
                    const int s = __shfl(ids, jj);
                    if (HASW) {
                        const float w = __shfl(wch, jj);
                        acc = fmaf(w, xin[(size_t)s * KIN + lane], acc);
                    } else {
                        acc += xin[(size_t)s * KIN + lane];
                    }
                }
            } else {  // KIN == 32: two half-waves split the edge list
                const int f = lane & 31, hf = lane >> 5;
                for (int jj = hf; jj < m; jj += 2) {
                    const int s = __shfl(ids, jj);
                    const float w = __shfl(wch, jj);
                    acc = fmaf(w, xin[(size_t)s * KIN + f], acc);
                }
            }
        }
        if (KIN == 32) acc += __shfl_xor(acc, 32);
        if (lane < KIN) agg[(size_t)n * KIN + lane] = acc;
    }
}

// ---------------- fused node linear + relu + pooling score ----------------
template<int KIN>
__global__ __launch_bounds__(256) void lin_score_kernel(
    const float* __restrict__ agg, const float* __restrict__ xin,
    const float* __restrict__ wr,  const float* __restrict__ br,
    const float* __restrict__ wk,  const float* __restrict__ pw,
    float* __restrict__ h, float* __restrict__ score)
{
    __shared__ float s_wrT[KIN * 64], s_wkT[KIN * 64], s_pw[64], s_br[64];
    const int tid = threadIdx.x;
    for (int i = tid; i < KIN * 64; i += 256) {
        const int k = i / 64, o = i % 64;          // transposed: [k][o]
        s_wrT[i] = wr[o * KIN + k];
        s_wkT[i] = wk[o * KIN + k];
    }
    if (tid < 64) { s_pw[tid] = pw[tid]; s_br[tid] = br[tid]; }
    __syncthreads();
    const int wave = tid >> 6, lane = tid & 63;
    const float pwv = s_pw[lane];
    float nrm2 = pwv * pwv;
    #pragma unroll
    for (int off = 32; off; off >>= 1) nrm2 += __shfl_xor(nrm2, off);
    const float inv_norm = rsqrtf(nrm2);

    #pragma unroll
    for (int rep = 0; rep < 4; ++rep) {
        const int node = (blockIdx.x << 4) + (rep << 2) + wave;
        const float* ar = agg + (size_t)node * KIN;
        const float* xr = xin + (size_t)node * KIN;
        float acc = s_br[lane];
        #pragma unroll
        for (int k = 0; k < KIN; k += 4) {
            float4 a4 = *(const float4*)(ar + k);
            float4 x4 = *(const float4*)(xr + k);
            acc = fmaf(a4.x, s_wrT[(k + 0) * 64 + lane], acc);
            acc = fmaf(a4.y, s_wrT[(k + 1) * 64 + lane], acc);
            acc = fmaf(a4.z, s_wrT[(k + 2) * 64 + lane], acc);
            acc = fmaf(a4.w, s_wrT[(k + 3) * 64 + lane], acc);
            acc = fmaf(x4.x, s_wkT[(k + 0) * 64 + lane], acc);
            acc = fmaf(x4.y, s_wkT[(k + 1) * 64 + lane], acc);
            acc = fmaf(x4.z, s_wkT[(k + 2) * 64 + lane], acc);
            acc = fmaf(x4.w, s_wkT[(k + 3) * 64 + lane], acc);
        }
        const float hv = fmaxf(acc, 0.f);
        h[(size_t)node * 64 + lane] = hv;
        float p = hv * pwv;
        #pragma unroll
        for (int off = 32; off; off >>= 1) p += __shfl_xor(p, off);
        if (lane == 0) score[node] = tanhf(p * inv_norm);
    }
}

// ---------------- per-graph top-k via bitonic sort ----------------
// total order: (score desc, index asc) — matches jax.lax.top_k tie-breaking.
template<int NREAL, int KSEL>
__global__ __launch_bounds__(512) void topk_kernel(
    const float* __restrict__ score, int* __restrict__ sel, int* __restrict__ nidx)
{
    __shared__ float sval[1024];
    __shared__ int   sidx[1024];
    const int g = blockIdx.x, tid = threadIdx.x;
    for (int i = tid; i < 1024; i += 512) {
        sval[i] = (i < NREAL) ? score[(size_t)g * NREAL + i] : -2.0f;
        sidx[i] = i;
    }
    __syncthreads();
    for (int k = 2; k <= 1024; k <<= 1)
        for (int j = k >> 1; j > 0; j >>= 1) {
            for (int i = tid; i < 1024; i += 512) {
                const int l = i ^ j;
                if (l > i) {
                    const float a = sval[i], bv = sval[l];
                    const int   ia = sidx[i], ib = sidx[l];
                    const bool swap_desc = (a < bv) || (a == bv && ia > ib);
                    if (swap_desc == ((i & k) == 0)) {
                        sval[i] = bv; sval[l] = a;
                        sidx[i] = ib; sidx[l] = ia;
                    }
                }
            }
            __syncthreads();
        }
    for (int j = tid; j < NREAL; j += 512) {
        const int node = sidx[j];
        if (j < KSEL) {
            sel[(size_t)g * KSEL + j] = node;
            nidx[(size_t)g * NREAL + node] = g * KSEL + j;
        } else {
            nidx[(size_t)g * NREAL + node] = -1;
        }
    }
}

// ---------------- pooled gather: xg[new] = h[old] * score[old] ----------------
__global__ __launch_bounds__(256) void gather_kernel(
    const float* __restrict__ h, const float* __restrict__ score,
    const int* __restrict__ sel, float* __restrict__ xg, int KSEL, int NPREV)
{
    const size_t i = (size_t)blockIdx.x * 256 + threadIdx.x;
    const int f = (int)(i & 63);
    const size_t n = i >> 6;
    const int g = (int)(n / KSEL);
    const int old = sel[n];
    const size_t oldg = (size_t)g * NPREV + old;
    xg[i] = h[oldg * 64 + f] * score[oldg];
}

// ---------------- readout: concat(max, mean) over k nodes ----------------
__global__ __launch_bounds__(256) void readout_kernel(
    const float* __restrict__ xg, float* __restrict__ out, int KSEL)
{
    const int g = blockIdx.x, tid = threadIdx.x;
    const int f = tid & 63, jc = tid >> 6;
    float mx = -3.4e38f, sm = 0.f;
    #pragma unroll 4
    for (int j = jc; j < KSEL; j += 4) {
        const float v = xg[((size_t)g * KSEL + j) * 64 + f];
        mx = fmaxf(mx, v); sm += v;
    }
    __shared__ float smx[256], ssm[256];
    smx[tid] = mx; ssm[tid] = sm;
    __syncthreads();
    if (tid < 64) {
        mx = fmaxf(fmaxf(smx[tid], smx[tid + 64]), fmaxf(smx[tid + 128], smx[tid + 192]));
        sm = ssm[tid] + ssm[tid + 64] + ssm[tid + 128] + ssm[tid + 192];
        out[g * 128 + tid] = mx;
        out[g * 128 + 64 + tid] = sm / (float)KSEL;
    }
}

// ---------------- final MLP + log_softmax (one wave per graph) ----------------
__global__ __launch_bounds__(64) void mlp_kernel(
    const float* __restrict__ x1, const float* __restrict__ x2, const float* __restrict__ x3,
    const float* __restrict__ w1, const float* __restrict__ b1,
    const float* __restrict__ w2, const float* __restrict__ b2,
    const float* __restrict__ w3, const float* __restrict__ b3,
    const float* __restrict__ w4, const float* __restrict__ b4,
    float* __restrict__ out)
{
    const int g = blockIdx.x, lane = threadIdx.x;
    __shared__ float z[128], a1[64], a2[32], a3[16], y[16], red[2];
    z[lane]      = x1[g * 128 + lane]      + x2[g * 128 + lane]      + x3[g * 128 + lane];
    z[lane + 64] = x1[g * 128 + 64 + lane] + x2[g * 128 + 64 + lane] + x3[g * 128 + 64 + lane];
    __syncthreads();
    float acc = b1[lane];
    #pragma unroll
    for (int k = 0; k < 128; ++k) acc = fmaf(z[k], w1[lane * 128 + k], acc);
    a1[lane] = fmaxf(acc, 0.f);
    __syncthreads();
    if (lane < 32) {
        float a = b2[lane];
        #pragma unroll
        for (int k = 0; k < 64; ++k) a = fmaf(a1[k], w2[lane * 64 + k], a);
        a2[lane] = fmaxf(a, 0.f);
    }
    __syncthreads();
    if (lane < 16) {
        float a = b3[lane];
        #pragma unroll
        for (int k = 0; k < 32; ++k) a = fmaf(a2[k], w3[lane * 32 + k], a);
        a3[lane] = fmaxf(a, 0.f);
    }
    __syncthreads();
    if (lane < NCLS) {
        float a = b4[lane];
        #pragma unroll
        for (int k = 0; k < 16; ++k) a = fmaf(a3[k], w4[lane * 16 + k], a);
        y[lane] = a;
    }
    __syncthreads();
    if (lane == 0) {
        float m = y[0];
        for (int c = 1; c < NCLS; ++c) m = fmaxf(m, y[c]);
        float s = 0.f;
        for (int c = 0; c < NCLS; ++c) s += expf(y[c] - m);
        red[0] = m; red[1] = logf(s);
    }
    __syncthreads();
    if (lane < NCLS) out[g * NCLS + lane] = y[lane] - red[0] - red[1];
}

// ---------------- workspace layout (bytes) ----------------
constexpr size_t OFF_H      = 0;                                     // B*N*64 f32
constexpr size_t OFF_AGG    = OFF_H      + (size_t)B * N * H * 4;
constexpr size_t OFF_XG     = OFF_AGG    + (size_t)B * N * H * 4;    // B*K1*64 f32
constexpr size_t OFF_SCORE  = OFF_XG     + (size_t)B * K1 * H * 4;
constexpr size_t OFF_SEL    = OFF_SCORE  + (size_t)B * N * 4;
constexpr size_t OFF_NIDX   = OFF_SEL    + (size_t)B * K1 * 4;
constexpr size_t OFF_CSRS   = OFF_NIDX   + (size_t)B * N * 4;        // B*E int
constexpr size_t OFF_CSRW   = OFF_CSRS   + (size_t)B * E * 4;        // B*E f32 (stage1) / esrc (stages 2,3)
constexpr size_t OFF_EDST   = OFF_CSRW   + (size_t)B * E * 4;        // B*E int
constexpr size_t OFF_ROW    = OFF_EDST   + (size_t)B * E * 4;        // B*(N+1) int
constexpr size_t OFF_X1     = OFF_ROW    + (size_t)B * (N + 1) * 4;
constexpr size_t OFF_X2     = OFF_X1     + (size_t)B * 128 * 4;
constexpr size_t OFF_X3     = OFF_X2     + (size_t)B * 128 * 4;

extern "C" void kernel_launch(void* const* d_in, const int* in_sizes, int n_in,
                              void* d_out, int out_size, void* d_ws, size_t ws_size,
                              hipStream_t stream)
{
    (void)in_sizes; (void)n_in; (void)out_size; (void)ws_size;
    const float* x     = (const float*)d_in[0];
    const int*   eidx  = (const int*)d_in[1];
    const float* eattr = (const float*)d_in[2];
    const int* src0 = eidx;
    const int* dst0 = eidx + (size_t)B * E;
    const float* c1_wr = (const float*)d_in[3],  *c1_br = (const float*)d_in[4];
    const float* c1_wk = (const float*)d_in[5],  *p1_w  = (const float*)d_in[6];
    const float* c2_wr = (const float*)d_in[7],  *c2_br = (const float*)d_in[8];
    const float* c2_wk = (const float*)d_in[9],  *p2_w  = (const float*)d_in[10];
    const float* c3_wr = (const float*)d_in[11], *c3_br = (const float*)d_in[12];
    const float* c3_wk = (const float*)d_in[13], *p3_w  = (const float*)d_in[14];
    const float* l1_w = (const float*)d_in[15], *l1_b = (const float*)d_in[16];
    const float* l2_w = (const float*)d_in[17], *l2_b = (const float*)d_in[18];
    const float* l3_w = (const float*)d_in[19], *l3_b = (const float*)d_in[20];
    const float* l4_w = (const float*)d_in[21], *l4_b = (const float*)d_in[22];

    char* ws = (char*)d_ws;
    float* h       = (float*)(ws + OFF_H);
    float* agg     = (float*)(ws + OFF_AGG);
    float* xg      = (float*)(ws + OFF_XG);
    float* score   = (float*)(ws + OFF_SCORE);
    int*   sel     = (int*)  (ws + OFF_SEL);
    int*   nidx    = (int*)  (ws + OFF_NIDX);
    int*   csr_src = (int*)  (ws + OFF_CSRS);
    float* csr_w   = (float*)(ws + OFF_CSRW);   // stage 1 weights
    int*   esrc    = (int*)  (ws + OFF_CSRW);   // stages 2/3 remapped src (aliases csr_w)
    int*   edst    = (int*)  (ws + OFF_EDST);
    int*   rowoff  = (int*)  (ws + OFF_ROW);
    float* x1      = (float*)(ws + OFF_X1);
    float* x2      = (float*)(ws + OFF_X2);
    float* x3      = (float*)(ws + OFF_X3);
    float* out     = (float*)d_out;

    // ---- stage 1 ----
    build_kernel<N, false, true><<<B, 1024, 0, stream>>>(
        src0, dst0, nullptr, eattr, nullptr, nullptr, rowoff, csr_src, csr_w);
    agg_csr_kernel<FIN, N, true><<<(B * N) / 32, 256, 0, stream>>>(
        x, csr_src, csr_w, rowoff, agg);
    lin_score_kernel<FIN><<<(B * N) / 16, 256, 0, stream>>>(
        agg, x, c1_wr, c1_br, c1_wk, p1_w, h, score);
    topk_kernel<N, K1><<<B, 512, 0, stream>>>(score, sel, nidx);
    gather_kernel<<<(B * K1 * 64) / 256, 256, 0, stream>>>(h, score, sel, xg, K1, N);
    readout_kernel<<<B, 256, 0, stream>>>(xg, x1, K1);

    // ---- stage 2 ----  (remap stage-1 edges through nidx1, build CSR over K1 nodes)
    build_kernel<K1, true, false><<<B, 1024, 0, stream>>>(
        src0, dst0, nidx, nullptr, esrc, edst, rowoff, csr_src, nullptr);
    agg_csr_kernel<H, K1, false><<<(B * K1) / 32, 256, 0, stream>>>(
        xg, csr_src, nullptr, rowoff, agg);
    lin_score_kernel<H><<<(B * K1) / 16, 256, 0, stream>>>(
        agg, xg, c2_wr, c2_br, c2_wk, p2_w, h, score);
    topk_kernel<K1, K2><<<B, 512, 0, stream>>>(score, sel, nidx);
    gather_kernel<<<(B * K2 * 64) / 256, 256, 0, stream>>>(h, score, sel, xg, K2, K1);
    readout_kernel<<<B, 256, 0, stream>>>(xg, x2, K2);

    // ---- stage 3 ----  (remap stage-2 edges in place through nidx2)
    build_kernel<K2, true, false><<<B, 1024, 0, stream>>>(
        esrc, edst, nidx, nullptr, esrc, edst, rowoff, csr_src, nullptr);
    agg_csr_kernel<H, K2, false><<<(B * K2) / 32, 256, 0, stream>>>(
        xg, csr_src, nullptr, rowoff, agg);
    lin_score_kernel<H><<<(B * K2) / 16, 256, 0, stream>>>(
        agg, xg, c3_wr, c3_br, c3_wk, p3_w, h, score);
    topk_kernel<K2, K3><<<B, 512, 0, stream>>>(score, sel, nidx);
    gather_kernel<<<(B * K3 * 64) / 256, 256, 0, stream>>>(h, score, sel, xg, K3, K2);
    readout_kernel<<<B, 256, 0, stream>>>(xg, x3, K3);

    // ---- head ----
    mlp_kernel<<<B, 64, 0, stream>>>(x1, x2, x3, l1_w, l1_b, l2_w, l2_b,
                                     l3_w, l3_b, l4_w, l4_b, out);
}

// Round 8
// 809.863 us; speedup vs baseline: 2.2212x; 1.3058x over previous
//
#include <hip/hip_runtime.h>
#include <math.h>

// ---------------- problem constants ----------------
constexpr int B  = 128;
constexpr int N  = 1024;
constexpr int E  = 16384;
constexpr int FIN = 32;
constexpr int H  = 64;
constexpr int K1 = 820, K2 = 656, K3 = 525;
constexpr int NCLS = 10;

// ---------------- CSR build: histogram + scan + scatter (1 block/graph) ----
// Optionally remaps edges through nidx (old-global -> new-global, -1 = drop)
// and writes the remapped edge list back out for the next stage's build.
template<int NPG, bool REMAP, bool HASW>
__global__ __launch_bounds__(1024) void build_kernel(
    const int* __restrict__ src_in, const int* __restrict__ dst_in,
    const int* __restrict__ nidx,  const float* __restrict__ w_in,
    int* __restrict__ esrc_out, int* __restrict__ edst_out,
    int* __restrict__ rowoff, int* __restrict__ csr_src, float* __restrict__ csr_w)
{
    __shared__ int cnt[1024];
    __shared__ int excl[1024];
    const int g = blockIdx.x, tid = threadIdx.x;
    cnt[tid] = 0;
    __syncthreads();
    const size_t gE = (size_t)g * E;
    int sreg[16], dreg[16];
    #pragma unroll
    for (int i = 0; i < 16; ++i) {
        const int e = tid + i * 1024;
        int s = src_in[gE + e], d = dst_in[gE + e];
        if (REMAP) {
            s = (s >= 0) ? nidx[s] : -1;
            d = (d >= 0) ? nidx[d] : -1;
            esrc_out[gE + e] = s;
            edst_out[gE + e] = d;
        }
        if (s < 0 || d < 0) { s = -1; d = -1; }
        sreg[i] = s; dreg[i] = d;
        if (d >= 0) atomicAdd(&cnt[d - g * NPG], 1);
    }
    __syncthreads();
    // exclusive scan over NPG counters (Hillis-Steele on 1024, padded)
    const int v = (tid < NPG) ? cnt[tid] : 0;
    excl[tid] = v;
    __syncthreads();
    int run = v;
    for (int dd = 1; dd < 1024; dd <<= 1) {
        const int t = (tid >= dd) ? excl[tid - dd] : 0;
        __syncthreads();
        run += t;
        excl[tid] = run;
        __syncthreads();
    }
    const int ex = run - v;                    // exclusive prefix
    if (tid < NPG) rowoff[(size_t)g * (NPG + 1) + tid] = ex;
    if (tid == NPG - 1) rowoff[(size_t)g * (NPG + 1) + NPG] = run;
    excl[tid] = ex;
    cnt[tid] = 0;
    __syncthreads();
    #pragma unroll
    for (int i = 0; i < 16; ++i) {
        const int d = dreg[i];
        if (d >= 0) {
            const int dl = d - g * NPG;
            const int pos = excl[dl] + atomicAdd(&cnt[dl], 1);
            csr_src[gE + pos] = sreg[i];
            if (HASW) csr_w[gE + pos] = w_in[gE + tid + i * 1024];
        }
    }
}

// ---------------- CSR gather-aggregate: agg[n] = sum_{e in row(n)} w_e * x[src_e]
// one wave per node (8 nodes/wave), lane = feature; no atomics, no LDS.
template<int KIN, int NPG, bool HASW>
__global__ __launch_bounds__(256) void agg_csr_kernel(
    const float* __restrict__ xin, const int* __restrict__ csr_src,
    const float* __restrict__ csr_w, const int* __restrict__ rowoff,
    float* __restrict__ agg)
{
    const int wave = threadIdx.x >> 6, lane = threadIdx.x & 63;
    const int nbase = (blockIdx.x * 4 + wave) * 8;
    #pragma unroll 2
    for (int rep = 0; rep < 8; ++rep) {
        const int n = nbase + rep;
        const int g = n / NPG, nl = n - g * NPG;
        const size_t gE = (size_t)g * E;
        const int start = rowoff[g * (NPG + 1) + nl];
        const int end   = rowoff[g * (NPG + 1) + nl + 1];
        float acc = 0.f;
        for (int j0 = start; j0 < end; j0 += 64) {
            const int m = end - j0 < 64 ? end - j0 : 64;
            const int idx = j0 + (lane < m ? lane : 0);
            const int ids = csr_src[gE + idx];
            float wch = 1.f;
            if (HASW) wch = csr_w[gE + idx];
            if (KIN == 64) {
                for (int jj = 0; jj < m; ++jj) {
                    const int s = __shfl(ids, jj);
                    if (HASW) {
                        const float w = __shfl(wch, jj);
                        acc = fmaf(w, xin[(size_t)s * KIN + lane], acc);
                    } else {
                        acc += xin[(size_t)s * KIN + lane];
                    }
                }
            } else {  // KIN == 32: two half-waves split the edge list
                const int f = lane & 31, hf = lane >> 5;
                for (int jj = hf; jj < m; jj += 2) {
                    const int s = __shfl(ids, jj);
                    const float w = __shfl(wch, jj);
                    acc = fmaf(w, xin[(size_t)s * KIN + f], acc);
                }
            }
        }
        if (KIN == 32) acc += __shfl_xor(acc, 32);
        if (lane < KIN) agg[(size_t)n * KIN + lane] = acc;
    }
}

// ---------------- fused node linear + relu + pooling score ----------------
// lane = node. A/X rows live in per-lane registers; weights are wave-uniform
// (compiler scalarizes to s_load + SGPR operands). No LDS, no shuffles.
template<int KIN>
__global__ __launch_bounds__(256) void lin_score_kernel(
    const float* __restrict__ agg, const float* __restrict__ xin,
    const float* __restrict__ wr,  const float* __restrict__ br,
    const float* __restrict__ wk,  const float* __restrict__ pw,
    float* __restrict__ h, float* __restrict__ score)
{
    const int node = blockIdx.x * 256 + threadIdx.x;
    float areg[KIN], xreg[KIN];
    const float4* ar = (const float4*)(agg + (size_t)node * KIN);
    const float4* xr = (const float4*)(xin + (size_t)node * KIN);
    #pragma unroll
    for (int j = 0; j < KIN / 4; ++j) {
        const float4 a = ar[j], xv = xr[j];
        areg[4 * j + 0] = a.x;  areg[4 * j + 1] = a.y;
        areg[4 * j + 2] = a.z;  areg[4 * j + 3] = a.w;
        xreg[4 * j + 0] = xv.x; xreg[4 * j + 1] = xv.y;
        xreg[4 * j + 2] = xv.z; xreg[4 * j + 3] = xv.w;
    }
    float nrm2 = 0.f;
    #pragma unroll
    for (int o = 0; o < 64; ++o) nrm2 = fmaf(pw[o], pw[o], nrm2);
    const float inv_norm = rsqrtf(nrm2);

    float4* hrow = (float4*)(h + (size_t)node * 64);
    float p = 0.f;
    for (int og = 0; og < 16; ++og) {          // 4 outputs per group
        float hq[4];
        #pragma unroll
        for (int q = 0; q < 4; ++q) {
            const int o = og * 4 + q;
            float acc = br[o];
            #pragma unroll
            for (int k = 0; k < KIN; ++k) {
                acc = fmaf(areg[k], wr[o * KIN + k], acc);
                acc = fmaf(xreg[k], wk[o * KIN + k], acc);
            }
            hq[q] = fmaxf(acc, 0.f);
            p = fmaf(hq[q], pw[o], p);
        }
        hrow[og] = make_float4(hq[0], hq[1], hq[2], hq[3]);
    }
    score[node] = tanhf(p * inv_norm);
}

// ---------------- per-graph top-k via bitonic sort ----------------
// total order: (score desc, index asc) — matches jax.lax.top_k tie-breaking.
template<int NREAL, int KSEL>
__global__ __launch_bounds__(512) void topk_kernel(
    const float* __restrict__ score, int* __restrict__ sel, int* __restrict__ nidx)
{
    __shared__ float sval[1024];
    __shared__ int   sidx[1024];
    const int g = blockIdx.x, tid = threadIdx.x;
    for (int i = tid; i < 1024; i += 512) {
        sval[i] = (i < NREAL) ? score[(size_t)g * NREAL + i] : -2.0f;
        sidx[i] = i;
    }
    __syncthreads();
    for (int k = 2; k <= 1024; k <<= 1)
        for (int j = k >> 1; j > 0; j >>= 1) {
            for (int i = tid; i < 1024; i += 512) {
                const int l = i ^ j;
                if (l > i) {
                    const float a = sval[i], bv = sval[l];
                    const int   ia = sidx[i], ib = sidx[l];
                    const bool swap_desc = (a < bv) || (a == bv && ia > ib);
                    if (swap_desc == ((i & k) == 0)) {
                        sval[i] = bv; sval[l] = a;
                        sidx[i] = ib; sidx[l] = ia;
                    }
                }
            }
            __syncthreads();
        }
    for (int j = tid; j < NREAL; j += 512) {
        const int node = sidx[j];
        if (j < KSEL) {
            sel[(size_t)g * KSEL + j] = node;
            nidx[(size_t)g * NREAL + node] = g * KSEL + j;
        } else {
            nidx[(size_t)g * NREAL + node] = -1;
        }
    }
}

// ---------------- pooled gather: xg[new] = h[old] * score[old] ----------------
__global__ __launch_bounds__(256) void gather_kernel(
    const float* __restrict__ h, const float* __restrict__ score,
    const int* __restrict__ sel, float* __restrict__ xg, int KSEL, int NPREV)
{
    const size_t i = (size_t)blockIdx.x * 256 + threadIdx.x;
    const int f = (int)(i & 63);
    const size_t n = i >> 6;
    const int g = (int)(n / KSEL);
    const int old = sel[n];
    const size_t oldg = (size_t)g * NPREV + old;
    xg[i] = h[oldg * 64 + f] * score[oldg];
}

// ---------------- readout: concat(max, mean) over k nodes ----------------
__global__ __launch_bounds__(256) void readout_kernel(
    const float* __restrict__ xg, float* __restrict__ out, int KSEL)
{
    const int g = blockIdx.x, tid = threadIdx.x;
    const int f = tid & 63, jc = tid >> 6;
    float mx = -3.4e38f, sm = 0.f;
    #pragma unroll 4
    for (int j = jc; j < KSEL; j += 4) {
        const float v = xg[((size_t)g * KSEL + j) * 64 + f];
        mx = fmaxf(mx, v); sm += v;
    }
    __shared__ float smx[256], ssm[256];
    smx[tid] = mx; ssm[tid] = sm;
    __syncthreads();
    if (tid < 64) {
        mx = fmaxf(fmaxf(smx[tid], smx[tid + 64]), fmaxf(smx[tid + 128], smx[tid + 192]));
        sm = ssm[tid] + ssm[tid + 64] + ssm[tid + 128] + ssm[tid + 192];
        out[g * 128 + tid] = mx;
        out[g * 128 + 64 + tid] = sm / (float)KSEL;
    }
}

// ---------------- final MLP + log_softmax (one wave per graph) ----------------
__global__ __launch_bounds__(64) void mlp_kernel(
    const float* __restrict__ x1, const float* __restrict__ x2, const float* __restrict__ x3,
    const float* __restrict__ w1, const float* __restrict__ b1,
    const float* __restrict__ w2, const float* __restrict__ b2,
    const float* __restrict__ w3, const float* __restrict__ b3,
    const float* __restrict__ w4, const float* __restrict__ b4,
    float* __restrict__ out)
{
    const int g = blockIdx.x, lane = threadIdx.x;
    __shared__ float z[128], a1[64], a2[32], a3[16], y[16], red[2];
    z[lane]      = x1[g * 128 + lane]      + x2[g * 128 + lane]      + x3[g * 128 + lane];
    z[lane + 64] = x1[g * 128 + 64 + lane] + x2[g * 128 + 64 + lane] + x3[g * 128 + 64 + lane];
    __syncthreads();
    float acc = b1[lane];
    #pragma unroll
    for (int k = 0; k < 128; ++k) acc = fmaf(z[k], w1[lane * 128 + k], acc);
    a1[lane] = fmaxf(acc, 0.f);
    __syncthreads();
    if (lane < 32) {
        float a = b2[lane];
        #pragma unroll
        for (int k = 0; k < 64; ++k) a = fmaf(a1[k], w2[lane * 64 + k], a);
        a2[lane] = fmaxf(a, 0.f);
    }
    __syncthreads();
    if (lane < 16) {
        float a = b3[lane];
        #pragma unroll
        for (int k = 0; k < 32; ++k) a = fmaf(a2[k], w3[lane * 32 + k], a);
        a3[lane] = fmaxf(a, 0.f);
    }
    __syncthreads();
    if (lane < NCLS) {
        float a = b4[lane];
        #pragma unroll
        for (int k = 0; k < 16; ++k) a = fmaf(a3[k], w4[lane * 16 + k], a);
        y[lane] = a;
    }
    __syncthreads();
    if (lane == 0) {
        float m = y[0];
        for (int c = 1; c < NCLS; ++c) m = fmaxf(m, y[c]);
        float s = 0.f;
        for (int c = 0; c < NCLS; ++c) s += expf(y[c] - m);
        red[0] = m; red[1] = logf(s);
    }
    __syncthreads();
    if (lane < NCLS) out[g * NCLS + lane] = y[lane] - red[0] - red[1];
}

// ---------------- workspace layout (bytes) ----------------
constexpr size_t OFF_H      = 0;                                     // B*N*64 f32
constexpr size_t OFF_AGG    = OFF_H      + (size_t)B * N * H * 4;
constexpr size_t OFF_XG     = OFF_AGG    + (size_t)B * N * H * 4;    // B*K1*64 f32
constexpr size_t OFF_SCORE  = OFF_XG     + (size_t)B * K1 * H * 4;
constexpr size_t OFF_SEL    = OFF_SCORE  + (size_t)B * N * 4;
constexpr size_t OFF_NIDX   = OFF_SEL    + (size_t)B * K1 * 4;
constexpr size_t OFF_CSRS   = OFF_NIDX   + (size_t)B * N * 4;        // B*E int
constexpr size_t OFF_CSRW   = OFF_CSRS   + (size_t)B * E * 4;        // B*E f32 (stage1) / esrc (stages 2,3)
constexpr size_t OFF_EDST   = OFF_CSRW   + (size_t)B * E * 4;        // B*E int
constexpr size_t OFF_ROW    = OFF_EDST   + (size_t)B * E * 4;        // B*(N+1) int
constexpr size_t OFF_X1     = OFF_ROW    + (size_t)B * (N + 1) * 4;
constexpr size_t OFF_X2     = OFF_X1     + (size_t)B * 128 * 4;
constexpr size_t OFF_X3     = OFF_X2     + (size_t)B * 128 * 4;

extern "C" void kernel_launch(void* const* d_in, const int* in_sizes, int n_in,
                              void* d_out, int out_size, void* d_ws, size_t ws_size,
                              hipStream_t stream)
{
    (void)in_sizes; (void)n_in; (void)out_size; (void)ws_size;
    const float* x     = (const float*)d_in[0];
    const int*   eidx  = (const int*)d_in[1];
    const float* eattr = (const float*)d_in[2];
    const int* src0 = eidx;
    const int* dst0 = eidx + (size_t)B * E;
    const float* c1_wr = (const float*)d_in[3],  *c1_br = (const float*)d_in[4];
    const float* c1_wk = (const float*)d_in[5],  *p1_w  = (const float*)d_in[6];
    const float* c2_wr = (const float*)d_in[7],  *c2_br = (const float*)d_in[8];
    const float* c2_wk = (const float*)d_in[9],  *p2_w  = (const float*)d_in[10];
    const float* c3_wr = (const float*)d_in[11], *c3_br = (const float*)d_in[12];
    const float* c3_wk = (const float*)d_in[13], *p3_w  = (const float*)d_in[14];
    const float* l1_w = (const float*)d_in[15], *l1_b = (const float*)d_in[16];
    const float* l2_w = (const float*)d_in[17], *l2_b = (const float*)d_in[18];
    const float* l3_w = (const float*)d_in[19], *l3_b = (const float*)d_in[20];
    const float* l4_w = (const float*)d_in[21], *l4_b = (const float*)d_in[22];

    char* ws = (char*)d_ws;
    float* h       = (float*)(ws + OFF_H);
    float* agg     = (float*)(ws + OFF_AGG);
    float* xg      = (float*)(ws + OFF_XG);
    float* score   = (float*)(ws + OFF_SCORE);
    int*   sel     = (int*)  (ws + OFF_SEL);
    int*   nidx    = (int*)  (ws + OFF_NIDX);
    int*   csr_src = (int*)  (ws + OFF_CSRS);
    float* csr_w   = (float*)(ws + OFF_CSRW);   // stage 1 weights
    int*   esrc    = (int*)  (ws + OFF_CSRW);   // stages 2/3 remapped src (aliases csr_w)
    int*   edst    = (int*)  (ws + OFF_EDST);
    int*   rowoff  = (int*)  (ws + OFF_ROW);
    float* x1      = (float*)(ws + OFF_X1);
    float* x2      = (float*)(ws + OFF_X2);
    float* x3      = (float*)(ws + OFF_X3);
    float* out     = (float*)d_out;

    // ---- stage 1 ----
    build_kernel<N, false, true><<<B, 1024, 0, stream>>>(
        src0, dst0, nullptr, eattr, nullptr, nullptr, rowoff, csr_src, csr_w);
    agg_csr_kernel<FIN, N, true><<<(B * N) / 32, 256, 0, stream>>>(
        x, csr_src, csr_w, rowoff, agg);
    lin_score_kernel<FIN><<<(B * N) / 256, 256, 0, stream>>>(
        agg, x, c1_wr, c1_br, c1_wk, p1_w, h, score);
    topk_kernel<N, K1><<<B, 512, 0, stream>>>(score, sel, nidx);
    gather_kernel<<<(B * K1 * 64) / 256, 256, 0, stream>>>(h, score, sel, xg, K1, N);
    readout_kernel<<<B, 256, 0, stream>>>(xg, x1, K1);

    // ---- stage 2 ----  (remap stage-1 edges through nidx1, build CSR over K1 nodes)
    build_kernel<K1, true, false><<<B, 1024, 0, stream>>>(
        src0, dst0, nidx, nullptr, esrc, edst, rowoff, csr_src, nullptr);
    agg_csr_kernel<H, K1, false><<<(B * K1) / 32, 256, 0, stream>>>(
        xg, csr_src, nullptr, rowoff, agg);
    lin_score_kernel<H><<<(B * K1) / 256, 256, 0, stream>>>(
        agg, xg, c2_wr, c2_br, c2_wk, p2_w, h, score);
    topk_kernel<K1, K2><<<B, 512, 0, stream>>>(score, sel, nidx);
    gather_kernel<<<(B * K2 * 64) / 256, 256, 0, stream>>>(h, score, sel, xg, K2, K1);
    readout_kernel<<<B, 256, 0, stream>>>(xg, x2, K2);

    // ---- stage 3 ----  (remap stage-2 edges in place through nidx2)
    build_kernel<K2, true, false><<<B, 1024, 0, stream>>>(
        esrc, edst, nidx, nullptr, esrc, edst, rowoff, csr_src, nullptr);
    agg_csr_kernel<H, K2, false><<<(B * K2) / 32, 256, 0, stream>>>(
        xg, csr_src, nullptr, rowoff, agg);
    lin_score_kernel<H><<<(B * K2) / 256, 256, 0, stream>>>(
        agg, xg, c3_wr, c3_br, c3_wk, p3_w, h, score);
    topk_kernel<K2, K3><<<B, 512, 0, stream>>>(score, sel, nidx);
    gather_kernel<<<(B * K3 * 64) / 256, 256, 0, stream>>>(h, score, sel, xg, K3, K2);
    readout_kernel<<<B, 256, 0, stream>>>(xg, x3, K3);

    // ---- head ----
    mlp_kernel<<<B, 64, 0, stream>>>(x1, x2, x3, l1_w, l1_b, l2_w, l2_b,
                                     l3_w, l3_b, l4_w, l4_b, out);
}